// Round 26
// baseline (133.162 us; speedup 1.0000x reference)
//
#include <hip/hip_runtime.h>
#include <cstddef>

#define NN 3072
#define RR 16
#define NB 16
#define FILL_BLOCKS 64

typedef float f32x4 __attribute__((ext_vector_type(4)));

// Prologue: key[i] = valid ? batch[i] : -1, plus batch row boundaries
// start[b] = first row with batch >= b (batch sorted). start[NB]=NN.
__global__ void frd_prep_kernel(const int* __restrict__ cls,
                                const int* __restrict__ batch,
                                int* __restrict__ key,
                                int* __restrict__ start) {
    int t = blockIdx.x * blockDim.x + threadIdx.x;
    if (t < NN) {
        int c = cls[t];
        int b = batch[t];
        key[t] = (c != 24 && c != 25 && c != 26) ? b : -1;
        int prev = (t == 0) ? -1 : batch[t - 1];
        for (int bb = prev + 1; bb <= b; ++bb) start[bb] = t;
        if (t == NN - 1)
            for (int bb = b + 1; bb <= NB; ++bb) start[bb] = NN;
    }
}

// Phase 2: row-structured NT fill, 64 blocks, with DEPTH-2 SCALAR PIPELINE:
// key[] fetched two rows ahead, start[] one row ahead — every scalar load has
// a full row-burst (~4600 cy) in flight before its value is needed, so the
// store stream never stalls on the per-row dependent chain (R25's ~14 us/block
// loss). Writes default to columns outside [s0,s1) of valid rows; whole row
// if invalid. Disjoint from diag's write set -> race-free across dispatches.
__global__ __launch_bounds__(256)
void frd_fill_kernel(const int* __restrict__ key,
                     const int* __restrict__ start,
                     float* __restrict__ out) {
    const int tid = threadIdx.x;
    const float d0 = ((tid & 3) == 0) ? 1.0f : 0.0f;   // one_hot(0,R) head
    const f32x4 r = {d0, 0.0f, 0.0f, 0.0f};
    const int rowquads = NN * 4;                        // 12288 quads per row

    int i = blockIdx.x;
    // Preamble: bounds for row i (one-time stall), key for row i+64.
    int e0c = 0, b1c = 0;
    {
        const int ki = key[i];
        if (ki >= 0) { e0c = start[ki] * 4; b1c = start[ki + 1] * 4; }
    }
    int k1 = (i + FILL_BLOCKS < NN) ? key[i + FILL_BLOCKS] : -1;

    while (i < NN) {
        // Issue key for row i+128 (used 2 iterations from now).
        const int i2 = i + 2 * FILL_BLOCKS;
        const int k2 = (i2 < NN) ? key[i2] : -1;
        // Issue start[] for row i+64 using k1 (loaded last iteration).
        const int sidx = (k1 >= 0) ? k1 : 0;            // branchless safe index
        const int sa = start[sidx];
        const int sb = start[sidx + 1];

        // Store burst for row i — bounds are 2-iterations-old registers.
        float* rowp = out + (size_t)i * NN * RR;
        for (int q = tid; q < e0c; q += 256)
            __builtin_nontemporal_store(r, reinterpret_cast<f32x4*>(rowp + (size_t)q * 4));
        for (int q = b1c + tid; q < rowquads; q += 256)
            __builtin_nontemporal_store(r, reinterpret_cast<f32x4*>(rowp + (size_t)q * 4));

        // Rotate pipeline (sa/sb first used here — after the burst).
        e0c = (k1 >= 0) ? sa * 4 : 0;
        b1c = (k1 >= 0) ? sb * 4 : 0;
        k1 = k2;
        i += FILL_BLOCKS;
    }
}

// Phase 3: batch-range writer. One block per row i (exit if key invalid).
// Writes the ENTIRE [s0,s1) range: product if key[j]==ki && seg_eff==0,
// else the default. 4 lanes per pair -> full 64 B coalesced lines.
__global__ __launch_bounds__(256)
void frd_diag_kernel(const float* __restrict__ z1,
                     const float* __restrict__ z2,
                     const float* __restrict__ seg,
                     const int* __restrict__ key,
                     const int* __restrict__ start,
                     float* __restrict__ out) {
    const int i = blockIdx.x;
    const int ki = key[i];
    if (ki < 0) return;
    const int s0 = start[ki];
    const int s1 = start[ki + 1];
    const int q = threadIdx.x & 3;
    const int g = threadIdx.x >> 2;       // pair group [0,64)

    const float4 a = *reinterpret_cast<const float4*>(z1 + i * RR + q * 4);
    const float d0 = (q == 0) ? 1.0f : 0.0f;

    for (int j = s0 + g; j < s1; j += 64) {
        f32x4 r = {d0, 0.0f, 0.0f, 0.0f};
        if (key[j] == ki) {
            const float s = seg[i * NN + j];          // 4-lane broadcast
            const float seg_eff = s + ((i == j) ? 1.0f : 0.0f);
            if (seg_eff == 0.0f) {
                const float4 b = *reinterpret_cast<const float4*>(z2 + j * RR + q * 4);
                r.x = a.x * b.x; r.y = a.y * b.y; r.z = a.z * b.z; r.w = a.w * b.w;
            }
        }
        float* op = out + ((size_t)i * NN + j) * RR + q * 4;
        __builtin_nontemporal_store(r, reinterpret_cast<f32x4*>(op));
    }
}

extern "C" void kernel_launch(void* const* d_in, const int* in_sizes, int n_in,
                              void* d_out, int out_size, void* d_ws, size_t ws_size,
                              hipStream_t stream) {
    const float* z1  = (const float*)d_in[0];
    const float* z2  = (const float*)d_in[1];
    const float* seg = (const float*)d_in[2];
    const int* cls   = (const int*)d_in[3];
    const int* batch = (const int*)d_in[4];
    float* out = (float*)d_out;
    int* key   = (int*)d_ws;
    int* start = key + NN;

    frd_prep_kernel<<<(NN + 255) / 256, 256, 0, stream>>>(cls, batch, key, start);
    frd_fill_kernel<<<FILL_BLOCKS, 256, 0, stream>>>(key, start, out);
    frd_diag_kernel<<<NN, 256, 0, stream>>>(z1, z2, seg, key, start, out);
}